// Round 3
// baseline (299.315 us; speedup 1.0000x reference)
//
#include <hip/hip_runtime.h>
#include <hip/hip_fp16.h>

#define S_LEN    1024
#define B_SZ     8
#define D_IN     64
#define D_OUT    96
#define NB       8
#define NE       (D_OUT * D_OUT)          // 9216
#define CHUNK    32                       // s-steps per recurrence chain
#define NCHUNK   (S_LEN / CHUNK)          // 32
#define NT_C     512                      // 8 waves (both roles)
#define WPB      (NE / NT_C)              // 18 producer blocks per chunk
#define NWBLK_F  (NCHUNK * WPB)           // 576 producer blocks
#define NT_W     256                      // fallback config
#define HPAD     104                      // f16 row pitch (52 words: 8-row quads tile 32 banks)
#define SPAD     100                      // f32 row pitch
#define XPAD     68
#define FLAG_STRIDE 16                    // ints -> 64B per flag line

__device__ __forceinline__ float cos_rev(float v) {   // cos(2*pi*v), v in revolutions
    v -= floorf(v);
    return __builtin_amdgcn_cosf(v);
}

// Nk dot: planar f16 W row (LDS, 8 lanes share -> broadcast) x f32 x-row.
__device__ __forceinline__ float nkdot(const __half* __restrict__ wrow,
                                       const float* __restrict__ xr) {
    float acc = 0.0f;
    #pragma unroll
    for (int h = 0; h < 2; ++h) {
        #pragma unroll
        for (int j = h * 6; j < h * 6 + 6; ++j) {
            float4 raw = *(const float4*)(wrow + 8 * j);
            const __half2* hp = (const __half2*)&raw;
            float2 c0 = __half22float2(hp[0]);
            float2 c1 = __half22float2(hp[1]);
            float2 c2 = __half22float2(hp[2]);
            float2 c3 = __half22float2(hp[3]);
            float4 x0 = *(const float4*)(xr + 8 * j);
            float4 x1 = *(const float4*)(xr + 8 * j + 4);
            acc = fmaf(c0.x, x0.x, acc); acc = fmaf(c0.y, x0.y, acc);
            acc = fmaf(c1.x, x0.z, acc); acc = fmaf(c1.y, x0.w, acc);
            acc = fmaf(c2.x, x1.x, acc); acc = fmaf(c2.y, x1.y, acc);
            acc = fmaf(c3.x, x1.z, acc); acc = fmaf(c3.y, x1.w, acc);
        }
    }
    return acc;
}

__device__ __forceinline__ void stage_W(__half* __restrict__ wh,
                                        const __half* __restrict__ Wg,
                                        int tid) {
    for (int cidx = tid; cidx < NE / 8; cidx += NT_C) {   // 1152 float4 chunks
        const int i = cidx / 12;
        const int j = (cidx % 12) * 8;
        *(float4*)(wh + i * HPAD + j) = *(const float4*)(Wg + cidx * 8);
    }
}

// ---------------- Fused producer+consumer with chunk-granular dependency ----------
// Tickets via atomicAdd: first 576 block-starts take W-producer role (chunk c,
// e-slice eb), rest take consumer role (s = t-576). A spinning consumer implies
// all producer blocks already STARTED (tickets are start-ordered) -> no deadlock.
// Cross-XCD visibility: producer __threadfence() before done++ (release);
// consumer __threadfence() after observing done==18 (acquire).  [G16]
// Proven internals unchanged: (i,b) mapping (row-per-lane was catastrophic in r1),
// HPAD=104 layout, 6-barrier chain, stage-after-barrier overlap.
__global__ void __launch_bounds__(NT_C)
fused(const float* __restrict__ seq,
      const float* __restrict__ M1, const float* __restrict__ Wres1,
      const float* __restrict__ M2,
      const float* __restrict__ g1, const float* __restrict__ b1,
      const float* __restrict__ g2, const float* __restrict__ b2,
      const float* __restrict__ P1, const float* __restrict__ P2,
      __half* __restrict__ W1g, __half* __restrict__ W2g,
      int* __restrict__ flags,      // done[c] at flags[c*16]; ctr at flags[32*16]
      float* __restrict__ out) {
    __shared__ __align__(16) __half wh [D_OUT * HPAD];   // 19968 B
    __shared__ __align__(16) float  xn [B_SZ * SPAD];    //  3200 B
    __shared__ __align__(16) float  x1b[B_SZ * SPAD];    //  3200 B; xin alias pre-Nk1
    __shared__ int s_ticket;

    const int tid = threadIdx.x;
    if (tid == 0) s_ticket = atomicAdd(flags + 32 * FLAG_STRIDE, 1);
    __syncthreads();
    const int t = s_ticket;

    if (t < NWBLK_F) {
        // ================= W-producer role =================
        const int c  = t / WPB;
        const int eb = t % WPB;
        const int e  = eb * NT_C + tid;
        const int s0 = c * CHUNK;
        const float s0f = (float)s0;

        float p1l[NB], p2l[NB];
        *(float4*)&p1l[0] = *(const float4*)(P1 + e * NB);
        *(float4*)&p1l[4] = *(const float4*)(P1 + e * NB + 4);
        *(float4*)&p2l[0] = *(const float4*)(P2 + e * NB);
        *(float4*)&p2l[4] = *(const float4*)(P2 + e * NB + 4);

        float cc[NB], cp[NB], kk[NB];
        #pragma unroll
        for (int g = 0; g < NB; ++g) {
            const float inv = __builtin_amdgcn_rcpf((float)(e * NB + 2 + g));
            cc[g] = cos_rev(s0f * inv);
            cp[g] = cos_rev((s0f - 1.0f) * inv);
            kk[g] = 2.0f * __builtin_amdgcn_cosf(inv);   // inv <= 0.5 rev
        }

        #pragma unroll 4
        for (int s = s0; s < s0 + CHUNK; ++s) {
            float a1 = 0.0f, a2 = 0.0f;
            #pragma unroll
            for (int g = 0; g < NB; ++g) {
                a1 = fmaf(p1l[g], cc[g], a1);
                a2 = fmaf(p2l[g], cc[g], a2);
            }
            W1g[s * NE + e] = __float2half(a1);   // coalesced 2B/lane
            W2g[s * NE + e] = __float2half(a2);
            #pragma unroll
            for (int g = 0; g < NB; ++g) {
                float cn = fmaf(kk[g], cc[g], -cp[g]);
                cp[g] = cc[g];
                cc[g] = cn;
            }
        }
        __threadfence();                          // release: stores device-visible
        __syncthreads();                          // all threads fenced
        if (tid == 0) atomicAdd(flags + c * FLAG_STRIDE, 1);
        return;
    }

    // ================= Consumer role =================
    const int s = t - NWBLK_F;
    const int c = s >> 5;                         // CHUNK=32

    // stage seq rows (loads in flight during the spin)
    {
        int b = tid >> 6, k = tid & 63;
        x1b[b * SPAD + k] = seq[((size_t)b * S_LEN + s) * D_IN + k];   // xin alias
    }
    if (tid == 0) {
        while (atomicAdd(flags + c * FLAG_STRIDE, 0) < WPB)
            __builtin_amdgcn_s_sleep(8);
        __threadfence();                          // acquire: invalidate stale lines
    }
    __syncthreads();   // B1 (seq staged + chunk c ready)

    stage_W(wh, W1g + (size_t)s * NE, tid);   // drains at B2, overlapped with GEMV1

    // ---- GEMV1: xt = seq@M1^T -> xn;  rs = seq@Wres1^T -> registers ----
    float ar0 = 0.0f, ar1 = 0.0f;
    for (int pass = 0; pass < 2; ++pass) {
        int idx = tid + pass * NT_C;
        if (idx >= B_SZ * D_OUT) break;
        int i = idx >> 3, b = idx & 7;
        const float4* m  = (const float4*)(M1 + i * D_IN);
        const float4* wr = (const float4*)(Wres1 + i * D_IN);
        const float*  xr = x1b + b * SPAD;   // xin alias
        float at = 0.0f, ar = 0.0f;
        #pragma unroll
        for (int k = 0; k < D_IN / 4; ++k) {
            float4 mv = m[k], rv = wr[k];
            float x0 = xr[4*k], x1 = xr[4*k+1], x2 = xr[4*k+2], x3 = xr[4*k+3];
            at = fmaf(mv.x, x0, fmaf(mv.y, x1, fmaf(mv.z, x2, fmaf(mv.w, x3, at))));
            ar = fmaf(rv.x, x0, fmaf(rv.y, x1, fmaf(rv.z, x2, fmaf(rv.w, x3, ar))));
        }
        xn[b * SPAD + i] = at;
        if (pass == 0) ar0 = ar; else ar1 = ar;
    }
    __syncthreads();   // B2  (xin alias dead from here; W1 staged)

    // ---- LN1: wave64 per batch row ----
    {
        const int b = tid >> 6, lane = tid & 63;
        const bool lo = (lane < 32);
        float* row = xn + b * SPAD;
        float v0 = row[lane];
        float v1 = lo ? row[64 + lane] : 0.0f;
        float sum = v0 + v1, sq = fmaf(v0, v0, v1 * v1);
        #pragma unroll
        for (int off = 32; off > 0; off >>= 1) {
            sum += __shfl_down(sum, off, 64);
            sq  += __shfl_down(sq,  off, 64);
        }
        sum = __shfl(sum, 0, 64);
        sq  = __shfl(sq,  0, 64);
        const float mu  = sum * (1.0f / 96.0f);
        const float var = fmaf(sq, 1.0f / 96.0f, -(mu * mu));
        const float rs  = rsqrtf(var + 1e-5f);
        row[lane] = fmaf((v0 - mu) * rs, g1[lane], b1[lane]);
        if (lo) row[64 + lane] = fmaf((v1 - mu) * rs, g1[64 + lane], b1[64 + lane]);
    }
    __syncthreads();   // B3

    // ---- Nk1 + residual(regs) -> x1b ----
    for (int pass = 0; pass < 2; ++pass) {
        int idx = tid + pass * NT_C;
        if (idx >= B_SZ * D_OUT) break;
        int i = idx >> 3, b = idx & 7;
        float ar = (pass == 0) ? ar0 : ar1;
        x1b[b * SPAD + i] = ar + nkdot(wh + i * HPAD, xn + b * SPAD);
    }
    __syncthreads();   // B4: W1 reads + x1b writes complete

    // restage wh <- W2[s]; GEMV2 overlaps (doesn't touch wh), B5 covers both.
    stage_W(wh, W2g + (size_t)s * NE, tid);

    // ---- GEMV2: xt2 = x1 @ M2^T -> xn ----
    for (int pass = 0; pass < 2; ++pass) {
        int idx = tid + pass * NT_C;
        if (idx >= B_SZ * D_OUT) break;
        int i = idx >> 3, b = idx & 7;
        const float4* m  = (const float4*)(M2 + i * D_OUT);
        const float*  xr = x1b + b * SPAD;
        float at = 0.0f;
        #pragma unroll
        for (int k = 0; k < D_OUT / 4; ++k) {
            float4 mv = m[k];
            at = fmaf(mv.x, xr[4*k], fmaf(mv.y, xr[4*k+1],
                 fmaf(mv.z, xr[4*k+2], fmaf(mv.w, xr[4*k+3], at))));
        }
        xn[b * SPAD + i] = at;
    }
    __syncthreads();   // B5

    // ---- LN2 ----
    {
        const int b = tid >> 6, lane = tid & 63;
        const bool lo = (lane < 32);
        float* row = xn + b * SPAD;
        float v0 = row[lane];
        float v1 = lo ? row[64 + lane] : 0.0f;
        float sum = v0 + v1, sq = fmaf(v0, v0, v1 * v1);
        #pragma unroll
        for (int off = 32; off > 0; off >>= 1) {
            sum += __shfl_down(sum, off, 64);
            sq  += __shfl_down(sq,  off, 64);
        }
        sum = __shfl(sum, 0, 64);
        sq  = __shfl(sq,  0, 64);
        const float mu  = sum * (1.0f / 96.0f);
        const float var = fmaf(sq, 1.0f / 96.0f, -(mu * mu));
        const float rs  = rsqrtf(var + 1e-5f);
        row[lane] = fmaf((v0 - mu) * rs, g2[lane], b2[lane]);
        if (lo) row[64 + lane] = fmaf((v1 - mu) * rs, g2[64 + lane], b2[64 + lane]);
    }
    __syncthreads();   // B6

    // ---- Nk2 + identity residual -> out ----
    for (int pass = 0; pass < 2; ++pass) {
        int idx = tid + pass * NT_C;
        if (idx >= B_SZ * D_OUT) break;
        int i = idx >> 3, b = idx & 7;
        float acc = nkdot(wh + i * HPAD, xn + b * SPAD);
        out[((size_t)b * S_LEN + s) * D_OUT + i] = acc + x1b[b * SPAD + i];
    }
}

// ---------------- Fallback (round-1 proven kernel) if ws too small ----------------
__global__ void __launch_bounds__(NT_W)
hier_fallback(const float* __restrict__ seq,  const float* __restrict__ M1,
              const float* __restrict__ P1,   const float* __restrict__ Wres1,
              const float* __restrict__ g1,   const float* __restrict__ b1,
              const float* __restrict__ M2,   const float* __restrict__ P2,
              const float* __restrict__ g2,   const float* __restrict__ b2,
              float* __restrict__ out) {
    __shared__ __align__(16) float w[D_OUT * SPAD];
    __shared__ __align__(16) float xin[B_SZ * XPAD];
    __shared__ __align__(16) float xn [B_SZ * SPAD];
    __shared__ __align__(16) float x1b[B_SZ * SPAD];
    const int s = blockIdx.x, tid = threadIdx.x;
    const float sf = (float)s;

    for (int idx = tid; idx < B_SZ * D_IN; idx += NT_W) {
        int b = idx >> 6, k = idx & (D_IN - 1);
        xin[b * XPAD + k] = seq[(b * S_LEN + s) * D_IN + k];
    }
    for (int e = tid; e < NE; e += NT_W) {
        float pl[8];
        *(float4*)&pl[0] = *(const float4*)(P1 + e * NB);
        *(float4*)&pl[4] = *(const float4*)(P1 + e * NB + 4);
        float acc = 0.0f;
        #pragma unroll
        for (int g = 0; g < NB; ++g) {
            float v = sf * __builtin_amdgcn_rcpf((float)(e * NB + 2 + g));
            acc = fmaf(pl[g], cos_rev(v), acc);
        }
        int i = e / D_OUT;
        w[e + (SPAD - D_OUT) * i] = acc;
    }
    __syncthreads();
    for (int idx = tid; idx < B_SZ * D_OUT; idx += NT_W) {
        int i = idx >> 3, b = idx & 7;
        const float4* m  = (const float4*)(M1 + i * D_IN);
        const float4* wr = (const float4*)(Wres1 + i * D_IN);
        const float*  xr = xin + b * XPAD;
        float at = 0.0f, ar = 0.0f;
        #pragma unroll
        for (int k = 0; k < D_IN / 4; ++k) {
            float4 mv = m[k], rv = wr[k];
            float x0 = xr[4*k], x1 = xr[4*k+1], x2 = xr[4*k+2], x3 = xr[4*k+3];
            at = fmaf(mv.x, x0, fmaf(mv.y, x1, fmaf(mv.z, x2, fmaf(mv.w, x3, at))));
            ar = fmaf(rv.x, x0, fmaf(rv.y, x1, fmaf(rv.z, x2, fmaf(rv.w, x3, ar))));
        }
        xn [b * SPAD + i] = at;
        x1b[b * SPAD + i] = ar;
    }
    __syncthreads();
    {
        const int b = tid >> 5, rr = tid & 31;
        float* row = xn + b * SPAD;
        float v0 = row[rr], v1 = row[rr + 32], v2 = row[rr + 64];
        float sum = v0 + v1 + v2, sq = fmaf(v0, v0, fmaf(v1, v1, v2 * v2));
        #pragma unroll
        for (int off = 16; off > 0; off >>= 1) {
            sum += __shfl_down(sum, off, 32);
            sq  += __shfl_down(sq,  off, 32);
        }
        sum = __shfl(sum, 0, 32); sq = __shfl(sq, 0, 32);
        float mu = sum * (1.0f/96.0f), var = fmaf(sq, 1.0f/96.0f, -(mu*mu));
        float rs = rsqrtf(var + 1e-5f);
        row[rr]      = fmaf((v0 - mu) * rs, g1[rr],      b1[rr]);
        row[rr + 32] = fmaf((v1 - mu) * rs, g1[rr + 32], b1[rr + 32]);
        row[rr + 64] = fmaf((v2 - mu) * rs, g1[rr + 64], b1[rr + 64]);
    }
    __syncthreads();
    for (int idx = tid; idx < B_SZ * D_OUT; idx += NT_W) {
        int i = idx >> 3, b = idx & 7;
        const float* wrow = w + i * SPAD;
        const float* xr   = xn + b * SPAD;
        float acc = 0.0f;
        #pragma unroll
        for (int j = 0; j < D_OUT / 4; ++j) {
            float4 wv = *(const float4*)(wrow + 4 * j);
            float4 xv = *(const float4*)(xr + 4 * j);
            acc = fmaf(wv.x, xv.x, fmaf(wv.y, xv.y, fmaf(wv.z, xv.z, fmaf(wv.w, xv.w, acc))));
        }
        x1b[b * SPAD + i] += acc;
    }
    __syncthreads();
    for (int e = tid; e < NE; e += NT_W) {
        float pl[8];
        *(float4*)&pl[0] = *(const float4*)(P2 + e * NB);
        *(float4*)&pl[4] = *(const float4*)(P2 + e * NB + 4);
        float acc = 0.0f;
        #pragma unroll
        for (int g = 0; g < NB; ++g) {
            float v = sf * __builtin_amdgcn_rcpf((float)(e * NB + 2 + g));
            acc = fmaf(pl[g], cos_rev(v), acc);
        }
        int i = e / D_OUT;
        w[e + (SPAD - D_OUT) * i] = acc;
    }
    for (int idx = tid; idx < B_SZ * D_OUT; idx += NT_W) {
        int i = idx >> 3, b = idx & 7;
        const float4* m  = (const float4*)(M2 + i * D_OUT);
        const float*  xr = x1b + b * SPAD;
        float at = 0.0f;
        #pragma unroll
        for (int k = 0; k < D_OUT / 4; ++k) {
            float4 mv = m[k];
            at = fmaf(mv.x, xr[4*k], fmaf(mv.y, xr[4*k+1],
                 fmaf(mv.z, xr[4*k+2], fmaf(mv.w, xr[4*k+3], at))));
        }
        xn[b * SPAD + i] = at;
    }
    __syncthreads();
    {
        const int b = tid >> 5, rr = tid & 31;
        float* row = xn + b * SPAD;
        float v0 = row[rr], v1 = row[rr + 32], v2 = row[rr + 64];
        float sum = v0 + v1 + v2, sq = fmaf(v0, v0, fmaf(v1, v1, v2 * v2));
        #pragma unroll
        for (int off = 16; off > 0; off >>= 1) {
            sum += __shfl_down(sum, off, 32);
            sq  += __shfl_down(sq,  off, 32);
        }
        sum = __shfl(sum, 0, 32); sq = __shfl(sq, 0, 32);
        float mu = sum * (1.0f/96.0f), var = fmaf(sq, 1.0f/96.0f, -(mu*mu));
        float rs = rsqrtf(var + 1e-5f);
        row[rr]      = fmaf((v0 - mu) * rs, g2[rr],      b2[rr]);
        row[rr + 32] = fmaf((v1 - mu) * rs, g2[rr + 32], b2[rr + 32]);
        row[rr + 64] = fmaf((v2 - mu) * rs, g2[rr + 64], b2[rr + 64]);
    }
    __syncthreads();
    for (int idx = tid; idx < B_SZ * D_OUT; idx += NT_W) {
        int i = idx >> 3, b = idx & 7;
        const float* wrow = w + i * SPAD;
        const float* xr   = xn + b * SPAD;
        float acc = 0.0f;
        #pragma unroll
        for (int j = 0; j < D_OUT / 4; ++j) {
            float4 wv = *(const float4*)(wrow + 4 * j);
            float4 xv = *(const float4*)(xr + 4 * j);
            acc = fmaf(wv.x, xv.x, fmaf(wv.y, xv.y, fmaf(wv.z, xv.z, fmaf(wv.w, xv.w, acc))));
        }
        out[(b * S_LEN + s) * D_OUT + i] = acc + x1b[b * SPAD + i];
    }
}

extern "C" void kernel_launch(void* const* d_in, const int* in_sizes, int n_in,
                              void* d_out, int out_size, void* d_ws, size_t ws_size,
                              hipStream_t stream) {
    const float* seq   = (const float*)d_in[0];
    const float* M1    = (const float*)d_in[1];
    const float* P1    = (const float*)d_in[2];
    const float* Wres1 = (const float*)d_in[3];
    const float* g1    = (const float*)d_in[4];
    const float* b1    = (const float*)d_in[5];
    const float* M2    = (const float*)d_in[6];
    const float* P2    = (const float*)d_in[7];
    const float* g2    = (const float*)d_in[8];
    const float* b2    = (const float*)d_in[9];
    float* out = (float*)d_out;

    const size_t wbytes   = (size_t)2 * S_LEN * NE * sizeof(__half);   // 37.75 MB
    const size_t flagsz   = (size_t)(32 * FLAG_STRIDE + FLAG_STRIDE) * sizeof(int);  // 2112 B
    const size_t need     = wbytes + 4096;
    if (ws_size >= need) {
        __half* W1   = (__half*)d_ws;
        __half* W2   = W1 + (size_t)S_LEN * NE;
        int*   flags = (int*)((char*)d_ws + wbytes);   // 256B-aligned offset
        hipMemsetAsync(flags, 0, flagsz, stream);      // flags are poisoned each iter
        fused<<<dim3(NWBLK_F + S_LEN), dim3(NT_C), 0, stream>>>(
            seq, M1, Wres1, M2, g1, b1, g2, b2, P1, P2, W1, W2, flags, out);
    } else {
        hier_fallback<<<dim3(S_LEN), dim3(NT_W), 0, stream>>>(
            seq, M1, P1, Wres1, g1, b1, M2, P2, g2, b2, out);
    }
}

// Round 4
// 125.702 us; speedup vs baseline: 2.3812x; 2.3812x over previous
//
#include <hip/hip_runtime.h>
#include <hip/hip_fp16.h>

#define S_LEN    1024
#define B_SZ     8
#define D_IN     64
#define D_OUT    96
#define NB       8
#define NE       (D_OUT * D_OUT)          // 9216
#define CHUNK    32                       // s-steps per recurrence chain
#define NCHUNK   (S_LEN / CHUNK)          // 32
#define NT_W     256
#define NWBLK    (NCHUNK * (NE / NT_W))   // 1152 blocks
#define NT_C     512                      // 8 waves
#define SPAD     100                      // f32 row pitch
#define XPAD     68

__device__ __forceinline__ float cos_rev(float v) {   // cos(2*pi*v), v in revolutions
    v -= floorf(v);
    return __builtin_amdgcn_cosf(v);
}

// ---------------- w_kernel: planar W1, W2 (f16) via cosine recurrence ----------------
// (unchanged from round-2 proven version)
__global__ void __launch_bounds__(NT_W)
w_kernel(const float* __restrict__ P1, const float* __restrict__ P2,
         __half* __restrict__ W1, __half* __restrict__ W2) {
    const int c  = blockIdx.x / (NE / NT_W);
    const int eb = blockIdx.x % (NE / NT_W);
    const int e  = eb * NT_W + threadIdx.x;
    const int s0 = c * CHUNK;
    const float s0f = (float)s0;

    float p1l[NB], p2l[NB];
    *(float4*)&p1l[0] = *(const float4*)(P1 + e * NB);
    *(float4*)&p1l[4] = *(const float4*)(P1 + e * NB + 4);
    *(float4*)&p2l[0] = *(const float4*)(P2 + e * NB);
    *(float4*)&p2l[4] = *(const float4*)(P2 + e * NB + 4);

    float cc[NB], cp[NB], kk[NB];
    #pragma unroll
    for (int g = 0; g < NB; ++g) {
        const float inv = __builtin_amdgcn_rcpf((float)(e * NB + 2 + g));
        cc[g] = cos_rev(s0f * inv);
        cp[g] = cos_rev((s0f - 1.0f) * inv);
        kk[g] = 2.0f * __builtin_amdgcn_cosf(inv);   // inv <= 0.5 rev
    }

    #pragma unroll 4
    for (int s = s0; s < s0 + CHUNK; ++s) {
        float a1 = 0.0f, a2 = 0.0f;
        #pragma unroll
        for (int g = 0; g < NB; ++g) {
            a1 = fmaf(p1l[g], cc[g], a1);
            a2 = fmaf(p2l[g], cc[g], a2);
        }
        W1[s * NE + e] = __float2half(a1);   // coalesced 2B/lane
        W2[s * NE + e] = __float2half(a2);
        #pragma unroll
        for (int g = 0; g < NB; ++g) {
            float cn = fmaf(kk[g], cc[g], -cp[g]);
            cp[g] = cc[g];
            cc[g] = cn;
        }
    }
}

// Nk dot, global-W variant: W row i (192B contiguous, L2/L3-resident) read as
// 12 dwordx4; 8 lanes of the wave read the SAME address -> coalescer broadcast,
// so each W segment is fetched once per block (same traffic as LDS staging).
// const __restrict__ + no W stores in this kernel => compiler may hoist these
// loads above preceding barriers, overlapping GEMV/LN automatically.
__device__ __forceinline__ float nkdot_g(const __half* __restrict__ wrow,
                                         const float* __restrict__ xr) {
    float acc = 0.0f;
    #pragma unroll
    for (int h = 0; h < 2; ++h) {
        #pragma unroll
        for (int j = h * 6; j < h * 6 + 6; ++j) {
            float4 raw = *(const float4*)(wrow + 8 * j);
            const __half2* hp = (const __half2*)&raw;
            float2 c0 = __half22float2(hp[0]);
            float2 c1 = __half22float2(hp[1]);
            float2 c2 = __half22float2(hp[2]);
            float2 c3 = __half22float2(hp[3]);
            float4 x0 = *(const float4*)(xr + 8 * j);
            float4 x1 = *(const float4*)(xr + 8 * j + 4);
            acc = fmaf(c0.x, x0.x, acc); acc = fmaf(c0.y, x0.y, acc);
            acc = fmaf(c1.x, x0.z, acc); acc = fmaf(c1.y, x0.w, acc);
            acc = fmaf(c2.x, x1.x, acc); acc = fmaf(c2.y, x1.y, acc);
            acc = fmaf(c3.x, x1.z, acc); acc = fmaf(c3.y, x1.w, acc);
        }
    }
    return acc;
}

// ---------------- Consumer: no LDS W staging; W read direct from global -----------
// 512 thr = 8 waves; 1024 blocks. LDS only 6.4 KB (xn + x1b).
// (i,b) mapping everywhere (row-per-lane was catastrophic in r1: 64 lines/instr).
// Role-fused single kernel was catastrophic in r3 (shared regalloc -> 36 VGPR,
// both paths spilled, 235us). NO min-waves clause (destructive VGPR caps r5/r9).
__global__ void __launch_bounds__(NT_C)
consumer(const float* __restrict__ seq,
         const float* __restrict__ M1, const float* __restrict__ Wres1,
         const float* __restrict__ M2,
         const float* __restrict__ g1, const float* __restrict__ b1,
         const float* __restrict__ g2, const float* __restrict__ b2,
         const __half* __restrict__ W1g, const __half* __restrict__ W2g,
         float* __restrict__ out) {
    __shared__ __align__(16) float  xn [B_SZ * SPAD];    //  3200 B
    __shared__ __align__(16) float  x1b[B_SZ * SPAD];    //  3200 B; xin alias pre-Nk1
    // total 6400 B

    const int s   = blockIdx.x;
    const int tid = threadIdx.x;

    // stage seq rows (into x1b alias space)
    {
        int b = tid >> 6, k = tid & 63;
        x1b[b * SPAD + k] = seq[((size_t)b * S_LEN + s) * D_IN + k];   // xin alias
    }
    __syncthreads();   // B1 (seq staged)

    // ---- GEMV1: xt = seq@M1^T -> xn;  rs = seq@Wres1^T -> registers ----
    float ar0 = 0.0f, ar1 = 0.0f;
    for (int pass = 0; pass < 2; ++pass) {
        int idx = tid + pass * NT_C;
        if (idx >= B_SZ * D_OUT) break;
        int i = idx >> 3, b = idx & 7;
        const float4* m  = (const float4*)(M1 + i * D_IN);
        const float4* wr = (const float4*)(Wres1 + i * D_IN);
        const float*  xr = x1b + b * SPAD;   // xin alias
        float at = 0.0f, ar = 0.0f;
        #pragma unroll
        for (int k = 0; k < D_IN / 4; ++k) {
            float4 mv = m[k], rv = wr[k];
            float x0 = xr[4*k], x1 = xr[4*k+1], x2 = xr[4*k+2], x3 = xr[4*k+3];
            at = fmaf(mv.x, x0, fmaf(mv.y, x1, fmaf(mv.z, x2, fmaf(mv.w, x3, at))));
            ar = fmaf(rv.x, x0, fmaf(rv.y, x1, fmaf(rv.z, x2, fmaf(rv.w, x3, ar))));
        }
        xn[b * SPAD + i] = at;
        if (pass == 0) ar0 = ar; else ar1 = ar;
    }
    __syncthreads();   // B2  (xin alias dead from here)

    // ---- LN1: wave64 per batch row ----
    {
        const int b = tid >> 6, lane = tid & 63;
        const bool lo = (lane < 32);
        float* row = xn + b * SPAD;
        float v0 = row[lane];
        float v1 = lo ? row[64 + lane] : 0.0f;
        float sum = v0 + v1, sq = fmaf(v0, v0, v1 * v1);
        #pragma unroll
        for (int off = 32; off > 0; off >>= 1) {
            sum += __shfl_down(sum, off, 64);
            sq  += __shfl_down(sq,  off, 64);
        }
        sum = __shfl(sum, 0, 64);
        sq  = __shfl(sq,  0, 64);
        const float mu  = sum * (1.0f / 96.0f);
        const float var = fmaf(sq, 1.0f / 96.0f, -(mu * mu));
        const float rs  = rsqrtf(var + 1e-5f);
        row[lane] = fmaf((v0 - mu) * rs, g1[lane], b1[lane]);
        if (lo) row[64 + lane] = fmaf((v1 - mu) * rs, g1[64 + lane], b1[64 + lane]);
    }
    __syncthreads();   // B3

    // ---- Nk1 + residual(regs) -> x1b ----
    {
        const __half* __restrict__ W1s = W1g + (size_t)s * NE;
        for (int pass = 0; pass < 2; ++pass) {
            int idx = tid + pass * NT_C;
            if (idx >= B_SZ * D_OUT) break;
            int i = idx >> 3, b = idx & 7;
            float ar = (pass == 0) ? ar0 : ar1;
            x1b[b * SPAD + i] = ar + nkdot_g(W1s + i * D_OUT, xn + b * SPAD);
        }
    }
    __syncthreads();   // B4: xn reads complete, x1b written

    // ---- GEMV2: xt2 = x1 @ M2^T -> xn ----
    for (int pass = 0; pass < 2; ++pass) {
        int idx = tid + pass * NT_C;
        if (idx >= B_SZ * D_OUT) break;
        int i = idx >> 3, b = idx & 7;
        const float4* m  = (const float4*)(M2 + i * D_OUT);
        const float*  xr = x1b + b * SPAD;
        float at = 0.0f;
        #pragma unroll
        for (int k = 0; k < D_OUT / 4; ++k) {
            float4 mv = m[k];
            at = fmaf(mv.x, xr[4*k], fmaf(mv.y, xr[4*k+1],
                 fmaf(mv.z, xr[4*k+2], fmaf(mv.w, xr[4*k+3], at))));
        }
        xn[b * SPAD + i] = at;
    }
    __syncthreads();   // B5

    // ---- LN2 ----
    {
        const int b = tid >> 6, lane = tid & 63;
        const bool lo = (lane < 32);
        float* row = xn + b * SPAD;
        float v0 = row[lane];
        float v1 = lo ? row[64 + lane] : 0.0f;
        float sum = v0 + v1, sq = fmaf(v0, v0, v1 * v1);
        #pragma unroll
        for (int off = 32; off > 0; off >>= 1) {
            sum += __shfl_down(sum, off, 64);
            sq  += __shfl_down(sq,  off, 64);
        }
        sum = __shfl(sum, 0, 64);
        sq  = __shfl(sq,  0, 64);
        const float mu  = sum * (1.0f / 96.0f);
        const float var = fmaf(sq, 1.0f / 96.0f, -(mu * mu));
        const float rs  = rsqrtf(var + 1e-5f);
        row[lane] = fmaf((v0 - mu) * rs, g2[lane], b2[lane]);
        if (lo) row[64 + lane] = fmaf((v1 - mu) * rs, g2[64 + lane], b2[64 + lane]);
    }
    __syncthreads();   // B6

    // ---- Nk2 + identity residual -> out ----
    {
        const __half* __restrict__ W2s = W2g + (size_t)s * NE;
        for (int pass = 0; pass < 2; ++pass) {
            int idx = tid + pass * NT_C;
            if (idx >= B_SZ * D_OUT) break;
            int i = idx >> 3, b = idx & 7;
            float acc = nkdot_g(W2s + i * D_OUT, xn + b * SPAD);
            out[((size_t)b * S_LEN + s) * D_OUT + i] = acc + x1b[b * SPAD + i];
        }
    }
}

// ---------------- Fallback (round-1 proven kernel) if ws too small ----------------
__global__ void __launch_bounds__(NT_W)
hier_fallback(const float* __restrict__ seq,  const float* __restrict__ M1,
              const float* __restrict__ P1,   const float* __restrict__ Wres1,
              const float* __restrict__ g1,   const float* __restrict__ b1,
              const float* __restrict__ M2,   const float* __restrict__ P2,
              const float* __restrict__ g2,   const float* __restrict__ b2,
              float* __restrict__ out) {
    __shared__ __align__(16) float w[D_OUT * SPAD];
    __shared__ __align__(16) float xin[B_SZ * XPAD];
    __shared__ __align__(16) float xn [B_SZ * SPAD];
    __shared__ __align__(16) float x1b[B_SZ * SPAD];
    const int s = blockIdx.x, tid = threadIdx.x;
    const float sf = (float)s;

    for (int idx = tid; idx < B_SZ * D_IN; idx += NT_W) {
        int b = idx >> 6, k = idx & (D_IN - 1);
        xin[b * XPAD + k] = seq[(b * S_LEN + s) * D_IN + k];
    }
    for (int e = tid; e < NE; e += NT_W) {
        float pl[8];
        *(float4*)&pl[0] = *(const float4*)(P1 + e * NB);
        *(float4*)&pl[4] = *(const float4*)(P1 + e * NB + 4);
        float acc = 0.0f;
        #pragma unroll
        for (int g = 0; g < NB; ++g) {
            float v = sf * __builtin_amdgcn_rcpf((float)(e * NB + 2 + g));
            acc = fmaf(pl[g], cos_rev(v), acc);
        }
        int i = e / D_OUT;
        w[e + (SPAD - D_OUT) * i] = acc;
    }
    __syncthreads();
    for (int idx = tid; idx < B_SZ * D_OUT; idx += NT_W) {
        int i = idx >> 3, b = idx & 7;
        const float4* m  = (const float4*)(M1 + i * D_IN);
        const float4* wr = (const float4*)(Wres1 + i * D_IN);
        const float*  xr = xin + b * XPAD;
        float at = 0.0f, ar = 0.0f;
        #pragma unroll
        for (int k = 0; k < D_IN / 4; ++k) {
            float4 mv = m[k], rv = wr[k];
            float x0 = xr[4*k], x1 = xr[4*k+1], x2 = xr[4*k+2], x3 = xr[4*k+3];
            at = fmaf(mv.x, x0, fmaf(mv.y, x1, fmaf(mv.z, x2, fmaf(mv.w, x3, at))));
            ar = fmaf(rv.x, x0, fmaf(rv.y, x1, fmaf(rv.z, x2, fmaf(rv.w, x3, ar))));
        }
        xn [b * SPAD + i] = at;
        x1b[b * SPAD + i] = ar;
    }
    __syncthreads();
    {
        const int b = tid >> 5, rr = tid & 31;
        float* row = xn + b * SPAD;
        float v0 = row[rr], v1 = row[rr + 32], v2 = row[rr + 64];
        float sum = v0 + v1 + v2, sq = fmaf(v0, v0, fmaf(v1, v1, v2 * v2));
        #pragma unroll
        for (int off = 16; off > 0; off >>= 1) {
            sum += __shfl_down(sum, off, 32);
            sq  += __shfl_down(sq,  off, 32);
        }
        sum = __shfl(sum, 0, 32); sq = __shfl(sq, 0, 32);
        float mu = sum * (1.0f/96.0f), var = fmaf(sq, 1.0f/96.0f, -(mu*mu));
        float rs = rsqrtf(var + 1e-5f);
        row[rr]      = fmaf((v0 - mu) * rs, g1[rr],      b1[rr]);
        row[rr + 32] = fmaf((v1 - mu) * rs, g1[rr + 32], b1[rr + 32]);
        row[rr + 64] = fmaf((v2 - mu) * rs, g1[rr + 64], b1[rr + 64]);
    }
    __syncthreads();
    for (int idx = tid; idx < B_SZ * D_OUT; idx += NT_W) {
        int i = idx >> 3, b = idx & 7;
        const float* wrow = w + i * SPAD;
        const float* xr   = xn + b * SPAD;
        float acc = 0.0f;
        #pragma unroll
        for (int j = 0; j < D_OUT / 4; ++j) {
            float4 wv = *(const float4*)(wrow + 4 * j);
            float4 xv = *(const float4*)(xr + 4 * j);
            acc = fmaf(wv.x, xv.x, fmaf(wv.y, xv.y, fmaf(wv.z, xv.z, fmaf(wv.w, xv.w, acc))));
        }
        x1b[b * SPAD + i] += acc;
    }
    __syncthreads();
    for (int e = tid; e < NE; e += NT_W) {
        float pl[8];
        *(float4*)&pl[0] = *(const float4*)(P2 + e * NB);
        *(float4*)&pl[4] = *(const float4*)(P2 + e * NB + 4);
        float acc = 0.0f;
        #pragma unroll
        for (int g = 0; g < NB; ++g) {
            float v = sf * __builtin_amdgcn_rcpf((float)(e * NB + 2 + g));
            acc = fmaf(pl[g], cos_rev(v), acc);
        }
        int i = e / D_OUT;
        w[e + (SPAD - D_OUT) * i] = acc;
    }
    for (int idx = tid; idx < B_SZ * D_OUT; idx += NT_W) {
        int i = idx >> 3, b = idx & 7;
        const float4* m  = (const float4*)(M2 + i * D_OUT);
        const float*  xr = x1b + b * SPAD;
        float at = 0.0f;
        #pragma unroll
        for (int k = 0; k < D_OUT / 4; ++k) {
            float4 mv = m[k];
            at = fmaf(mv.x, xr[4*k], fmaf(mv.y, xr[4*k+1],
                 fmaf(mv.z, xr[4*k+2], fmaf(mv.w, xr[4*k+3], at))));
        }
        xn[b * SPAD + i] = at;
    }
    __syncthreads();
    {
        const int b = tid >> 5, rr = tid & 31;
        float* row = xn + b * SPAD;
        float v0 = row[rr], v1 = row[rr + 32], v2 = row[rr + 64];
        float sum = v0 + v1 + v2, sq = fmaf(v0, v0, fmaf(v1, v1, v2 * v2));
        #pragma unroll
        for (int off = 16; off > 0; off >>= 1) {
            sum += __shfl_down(sum, off, 32);
            sq  += __shfl_down(sq,  off, 32);
        }
        sum = __shfl(sum, 0, 32); sq = __shfl(sq, 0, 32);
        float mu = sum * (1.0f/96.0f), var = fmaf(sq, 1.0f/96.0f, -(mu*mu));
        float rs = rsqrtf(var + 1e-5f);
        row[rr]      = fmaf((v0 - mu) * rs, g2[rr],      b2[rr]);
        row[rr + 32] = fmaf((v1 - mu) * rs, g2[rr + 32], b2[rr + 32]);
        row[rr + 64] = fmaf((v2 - mu) * rs, g2[rr + 64], b2[rr + 64]);
    }
    __syncthreads();
    for (int idx = tid; idx < B_SZ * D_OUT; idx += NT_W) {
        int i = idx >> 3, b = idx & 7;
        const float* wrow = w + i * SPAD;
        const float* xr   = xn + b * SPAD;
        float acc = 0.0f;
        #pragma unroll
        for (int j = 0; j < D_OUT / 4; ++j) {
            float4 wv = *(const float4*)(wrow + 4 * j);
            float4 xv = *(const float4*)(xr + 4 * j);
            acc = fmaf(wv.x, xv.x, fmaf(wv.y, xv.y, fmaf(wv.z, xv.z, fmaf(wv.w, xv.w, acc))));
        }
        out[(b * S_LEN + s) * D_OUT + i] = acc + x1b[b * SPAD + i];
    }
}

extern "C" void kernel_launch(void* const* d_in, const int* in_sizes, int n_in,
                              void* d_out, int out_size, void* d_ws, size_t ws_size,
                              hipStream_t stream) {
    const float* seq   = (const float*)d_in[0];
    const float* M1    = (const float*)d_in[1];
    const float* P1    = (const float*)d_in[2];
    const float* Wres1 = (const float*)d_in[3];
    const float* g1    = (const float*)d_in[4];
    const float* b1    = (const float*)d_in[5];
    const float* M2    = (const float*)d_in[6];
    const float* P2    = (const float*)d_in[7];
    const float* g2    = (const float*)d_in[8];
    const float* b2    = (const float*)d_in[9];
    float* out = (float*)d_out;

    const size_t need = (size_t)2 * S_LEN * NE * sizeof(__half);   // 37.75 MB
    if (ws_size >= need) {
        __half* W1 = (__half*)d_ws;
        __half* W2 = W1 + (size_t)S_LEN * NE;
        w_kernel<<<dim3(NWBLK), dim3(NT_W), 0, stream>>>(P1, P2, W1, W2);
        consumer<<<dim3(S_LEN), dim3(NT_C), 0, stream>>>(
            seq, M1, Wres1, M2, g1, b1, g2, b2, W1, W2, out);
    } else {
        hier_fallback<<<dim3(S_LEN), dim3(NT_W), 0, stream>>>(
            seq, M1, P1, Wres1, g1, b1, M2, P2, g2, b2, out);
    }
}

// Round 5
// 118.304 us; speedup vs baseline: 2.5300x; 1.0625x over previous
//
#include <hip/hip_runtime.h>
#include <hip/hip_fp16.h>

#define S_LEN    1024
#define B_SZ     8
#define D_IN     64
#define D_OUT    96
#define NB       8
#define NE       (D_OUT * D_OUT)          // 9216
#define CHUNK    32                       // s-steps per recurrence chain
#define NCHUNK   (S_LEN / CHUNK)          // 32
#define NT_W     256
#define NWBLK    (NCHUNK * (NE / NT_W))   // 1152 blocks
#define NT_C     512                      // 8 waves
#define HPAD     104                      // f16 row pitch (52 words: 8-row quads tile 32 banks; 52*48 ≡ 0 mod 32 so rows i and i+48 share the pattern)
#define SPAD     100                      // f32 row pitch
#define XPAD     68

__device__ __forceinline__ float cos_rev(float v) {   // cos(2*pi*v), v in revolutions
    v -= floorf(v);
    return __builtin_amdgcn_cosf(v);
}

// ---------------- w_kernel: planar W1, W2 (f16) via cosine recurrence ----------------
// (unchanged, r2-proven)
__global__ void __launch_bounds__(NT_W)
w_kernel(const float* __restrict__ P1, const float* __restrict__ P2,
         __half* __restrict__ W1, __half* __restrict__ W2) {
    const int c  = blockIdx.x / (NE / NT_W);
    const int eb = blockIdx.x % (NE / NT_W);
    const int e  = eb * NT_W + threadIdx.x;
    const int s0 = c * CHUNK;
    const float s0f = (float)s0;

    float p1l[NB], p2l[NB];
    *(float4*)&p1l[0] = *(const float4*)(P1 + e * NB);
    *(float4*)&p1l[4] = *(const float4*)(P1 + e * NB + 4);
    *(float4*)&p2l[0] = *(const float4*)(P2 + e * NB);
    *(float4*)&p2l[4] = *(const float4*)(P2 + e * NB + 4);

    float cc[NB], cp[NB], kk[NB];
    #pragma unroll
    for (int g = 0; g < NB; ++g) {
        const float inv = __builtin_amdgcn_rcpf((float)(e * NB + 2 + g));
        cc[g] = cos_rev(s0f * inv);
        cp[g] = cos_rev((s0f - 1.0f) * inv);
        kk[g] = 2.0f * __builtin_amdgcn_cosf(inv);   // inv <= 0.5 rev
    }

    #pragma unroll 4
    for (int s = s0; s < s0 + CHUNK; ++s) {
        float a1 = 0.0f, a2 = 0.0f;
        #pragma unroll
        for (int g = 0; g < NB; ++g) {
            a1 = fmaf(p1l[g], cc[g], a1);
            a2 = fmaf(p2l[g], cc[g], a2);
        }
        W1[s * NE + e] = __float2half(a1);   // coalesced 2B/lane
        W2[s * NE + e] = __float2half(a2);
        #pragma unroll
        for (int g = 0; g < NB; ++g) {
            float cn = fmaf(kk[g], cc[g], -cp[g]);
            cp[g] = cc[g];
            cc[g] = cn;
        }
    }
}

// Dual-row Nk dot: one x-row read (24 b128) feeds TWO W rows (i, i+48).
// Per-output LDS instrs: 36 -> 24. fma order per output identical to the
// proven single-row nkdot (bit-identical results). 8 lanes share each W row
// (broadcast); x rows conflict-free (8 distinct banks per 8-lane group).
__device__ __forceinline__ void nkdot2(const __half* __restrict__ w0,
                                       const __half* __restrict__ w1,
                                       const float* __restrict__ xr,
                                       float& a0, float& a1) {
    #pragma unroll
    for (int h = 0; h < 2; ++h) {          // two 6-chunk halves bound in-flight regs
        #pragma unroll
        for (int j = h * 6; j < h * 6 + 6; ++j) {
            float4 xa = *(const float4*)(xr + 8 * j);
            float4 xb = *(const float4*)(xr + 8 * j + 4);
            float4 r0 = *(const float4*)(w0 + 8 * j);
            float4 r1 = *(const float4*)(w1 + 8 * j);
            const __half2* h0 = (const __half2*)&r0;
            const __half2* h1 = (const __half2*)&r1;
            float2 c;
            c = __half22float2(h0[0]); a0 = fmaf(c.x, xa.x, a0); a0 = fmaf(c.y, xa.y, a0);
            c = __half22float2(h0[1]); a0 = fmaf(c.x, xa.z, a0); a0 = fmaf(c.y, xa.w, a0);
            c = __half22float2(h0[2]); a0 = fmaf(c.x, xb.x, a0); a0 = fmaf(c.y, xb.y, a0);
            c = __half22float2(h0[3]); a0 = fmaf(c.x, xb.z, a0); a0 = fmaf(c.y, xb.w, a0);
            c = __half22float2(h1[0]); a1 = fmaf(c.x, xa.x, a1); a1 = fmaf(c.y, xa.y, a1);
            c = __half22float2(h1[1]); a1 = fmaf(c.x, xa.z, a1); a1 = fmaf(c.y, xa.w, a1);
            c = __half22float2(h1[2]); a1 = fmaf(c.x, xb.x, a1); a1 = fmaf(c.y, xb.y, a1);
            c = __half22float2(h1[3]); a1 = fmaf(c.x, xb.z, a1); a1 = fmaf(c.y, xb.w, a1);
        }
    }
}

__device__ __forceinline__ void stage_W(__half* __restrict__ wh,
                                        const __half* __restrict__ Wg,
                                        int tid) {
    for (int cidx = tid; cidx < NE / 8; cidx += NT_C) {   // 1152 float4 chunks
        const int i = cidx / 12;
        const int j = (cidx % 12) * 8;
        *(float4*)(wh + i * HPAD + j) = *(const float4*)(Wg + cidx * 8);
    }
}

// ---------------- Consumer: r2 structure + dual-row Nk (fewer LDS instrs) ---------
// 512 thr = 8 waves; 1024 blocks = exactly 4/CU. (i,b) broadcast mapping everywhere
// (row-per-lane catastrophic in r1; role-fusion catastrophic in r3; global-W nkdot
// regressed in r4). Residual rs now goes through rsb LDS (Nk mapping differs from
// GEMV1's). LDS 29.6 KB -> still >=4 blocks/CU.
__global__ void __launch_bounds__(NT_C)
consumer(const float* __restrict__ seq,
         const float* __restrict__ M1, const float* __restrict__ Wres1,
         const float* __restrict__ M2,
         const float* __restrict__ g1, const float* __restrict__ b1,
         const float* __restrict__ g2, const float* __restrict__ b2,
         const __half* __restrict__ W1g, const __half* __restrict__ W2g,
         float* __restrict__ out) {
    __shared__ __align__(16) __half wh [D_OUT * HPAD];   // 19968 B (one layer at a time)
    __shared__ __align__(16) float  xn [B_SZ * SPAD];    //  3200 B
    __shared__ __align__(16) float  x1b[B_SZ * SPAD];    //  3200 B; xin alias pre-Nk1
    __shared__ __align__(16) float  rsb[B_SZ * SPAD];    //  3200 B residual
    // total 29568 B

    const int s   = blockIdx.x;
    const int tid = threadIdx.x;

    // stage seq rows (into x1b alias space); W1 stage after B1 (drains at B2,
    // hidden under GEMV1 which never touches wh)  [r2-proven]
    {
        int b = tid >> 6, k = tid & 63;
        x1b[b * SPAD + k] = seq[((size_t)b * S_LEN + s) * D_IN + k];   // xin alias
    }
    __syncthreads();   // B1 (seq staged)

    stage_W(wh, W1g + (size_t)s * NE, tid);

    // ---- GEMV1: xt = seq@M1^T -> xn;  rs = seq@Wres1^T -> rsb ----
    for (int pass = 0; pass < 2; ++pass) {
        int idx = tid + pass * NT_C;
        if (idx >= B_SZ * D_OUT) break;
        int i = idx >> 3, b = idx & 7;
        const float4* m  = (const float4*)(M1 + i * D_IN);
        const float4* wr = (const float4*)(Wres1 + i * D_IN);
        const float*  xr = x1b + b * SPAD;   // xin alias
        float at = 0.0f, ar = 0.0f;
        #pragma unroll
        for (int k = 0; k < D_IN / 4; ++k) {
            float4 mv = m[k], rv = wr[k];
            float x0 = xr[4*k], x1 = xr[4*k+1], x2 = xr[4*k+2], x3 = xr[4*k+3];
            at = fmaf(mv.x, x0, fmaf(mv.y, x1, fmaf(mv.z, x2, fmaf(mv.w, x3, at))));
            ar = fmaf(rv.x, x0, fmaf(rv.y, x1, fmaf(rv.z, x2, fmaf(rv.w, x3, ar))));
        }
        xn [b * SPAD + i] = at;
        rsb[b * SPAD + i] = ar;
    }
    __syncthreads();   // B2  (xin alias dead from here; W1 staged)

    // ---- LN1: wave64 per batch row ----
    {
        const int b = tid >> 6, lane = tid & 63;
        const bool lo = (lane < 32);
        float* row = xn + b * SPAD;
        float v0 = row[lane];
        float v1 = lo ? row[64 + lane] : 0.0f;
        float sum = v0 + v1, sq = fmaf(v0, v0, v1 * v1);
        #pragma unroll
        for (int off = 32; off > 0; off >>= 1) {
            sum += __shfl_down(sum, off, 64);
            sq  += __shfl_down(sq,  off, 64);
        }
        sum = __shfl(sum, 0, 64);
        sq  = __shfl(sq,  0, 64);
        const float mu  = sum * (1.0f / 96.0f);
        const float var = fmaf(sq, 1.0f / 96.0f, -(mu * mu));
        const float rs  = rsqrtf(var + 1e-5f);
        row[lane] = fmaf((v0 - mu) * rs, g1[lane], b1[lane]);
        if (lo) row[64 + lane] = fmaf((v1 - mu) * rs, g1[64 + lane], b1[64 + lane]);
    }
    __syncthreads();   // B3

    // ---- Nk1 + residual(rsb) -> x1b : dual-row, 384 threads ----
    if (tid < 8 * 48) {
        const int b  = tid & 7;
        const int ip = tid >> 3;              // 0..47 -> rows ip, ip+48
        float a0 = 0.0f, a1 = 0.0f;
        nkdot2(wh + ip * HPAD, wh + (ip + 48) * HPAD, xn + b * SPAD, a0, a1);
        x1b[b * SPAD + ip]      = rsb[b * SPAD + ip]      + a0;
        x1b[b * SPAD + ip + 48] = rsb[b * SPAD + ip + 48] + a1;
    }
    __syncthreads();   // B4: W1 reads + x1b writes complete

    // restage wh <- W2[s]; GEMV2 overlaps (doesn't touch wh), B5 covers both.
    stage_W(wh, W2g + (size_t)s * NE, tid);

    // ---- GEMV2: xt2 = x1 @ M2^T -> xn ----
    for (int pass = 0; pass < 2; ++pass) {
        int idx = tid + pass * NT_C;
        if (idx >= B_SZ * D_OUT) break;
        int i = idx >> 3, b = idx & 7;
        const float4* m  = (const float4*)(M2 + i * D_OUT);
        const float*  xr = x1b + b * SPAD;
        float at = 0.0f;
        #pragma unroll
        for (int k = 0; k < D_OUT / 4; ++k) {
            float4 mv = m[k];
            at = fmaf(mv.x, xr[4*k], fmaf(mv.y, xr[4*k+1],
                 fmaf(mv.z, xr[4*k+2], fmaf(mv.w, xr[4*k+3], at))));
        }
        xn[b * SPAD + i] = at;
    }
    __syncthreads();   // B5

    // ---- LN2 ----
    {
        const int b = tid >> 6, lane = tid & 63;
        const bool lo = (lane < 32);
        float* row = xn + b * SPAD;
        float v0 = row[lane];
        float v1 = lo ? row[64 + lane] : 0.0f;
        float sum = v0 + v1, sq = fmaf(v0, v0, v1 * v1);
        #pragma unroll
        for (int off = 32; off > 0; off >>= 1) {
            sum += __shfl_down(sum, off, 64);
            sq  += __shfl_down(sq,  off, 64);
        }
        sum = __shfl(sum, 0, 64);
        sq  = __shfl(sq,  0, 64);
        const float mu  = sum * (1.0f / 96.0f);
        const float var = fmaf(sq, 1.0f / 96.0f, -(mu * mu));
        const float rs  = rsqrtf(var + 1e-5f);
        row[lane] = fmaf((v0 - mu) * rs, g2[lane], b2[lane]);
        if (lo) row[64 + lane] = fmaf((v1 - mu) * rs, g2[64 + lane], b2[64 + lane]);
    }
    __syncthreads();   // B6

    // ---- Nk2 + identity residual -> out : dual-row, 384 threads ----
    if (tid < 8 * 48) {
        const int b  = tid & 7;
        const int ip = tid >> 3;
        float a0 = 0.0f, a1 = 0.0f;
        nkdot2(wh + ip * HPAD, wh + (ip + 48) * HPAD, xn + b * SPAD, a0, a1);
        const size_t base = ((size_t)b * S_LEN + s) * D_OUT;
        out[base + ip]      = a0 + x1b[b * SPAD + ip];
        out[base + ip + 48] = a1 + x1b[b * SPAD + ip + 48];
    }
}

// ---------------- Fallback (round-1 proven kernel) if ws too small ----------------
__global__ void __launch_bounds__(NT_W)
hier_fallback(const float* __restrict__ seq,  const float* __restrict__ M1,
              const float* __restrict__ P1,   const float* __restrict__ Wres1,
              const float* __restrict__ g1,   const float* __restrict__ b1,
              const float* __restrict__ M2,   const float* __restrict__ P2,
              const float* __restrict__ g2,   const float* __restrict__ b2,
              float* __restrict__ out) {
    __shared__ __align__(16) float w[D_OUT * SPAD];
    __shared__ __align__(16) float xin[B_SZ * XPAD];
    __shared__ __align__(16) float xn [B_SZ * SPAD];
    __shared__ __align__(16) float x1b[B_SZ * SPAD];
    const int s = blockIdx.x, tid = threadIdx.x;
    const float sf = (float)s;

    for (int idx = tid; idx < B_SZ * D_IN; idx += NT_W) {
        int b = idx >> 6, k = idx & (D_IN - 1);
        xin[b * XPAD + k] = seq[(b * S_LEN + s) * D_IN + k];
    }
    for (int e = tid; e < NE; e += NT_W) {
        float pl[8];
        *(float4*)&pl[0] = *(const float4*)(P1 + e * NB);
        *(float4*)&pl[4] = *(const float4*)(P1 + e * NB + 4);
        float acc = 0.0f;
        #pragma unroll
        for (int g = 0; g < NB; ++g) {
            float v = sf * __builtin_amdgcn_rcpf((float)(e * NB + 2 + g));
            acc = fmaf(pl[g], cos_rev(v), acc);
        }
        int i = e / D_OUT;
        w[e + (SPAD - D_OUT) * i] = acc;
    }
    __syncthreads();
    for (int idx = tid; idx < B_SZ * D_OUT; idx += NT_W) {
        int i = idx >> 3, b = idx & 7;
        const float4* m  = (const float4*)(M1 + i * D_IN);
        const float4* wr = (const float4*)(Wres1 + i * D_IN);
        const float*  xr = xin + b * XPAD;
        float at = 0.0f, ar = 0.0f;
        #pragma unroll
        for (int k = 0; k < D_IN / 4; ++k) {
            float4 mv = m[k], rv = wr[k];
            float x0 = xr[4*k], x1 = xr[4*k+1], x2 = xr[4*k+2], x3 = xr[4*k+3];
            at = fmaf(mv.x, x0, fmaf(mv.y, x1, fmaf(mv.z, x2, fmaf(mv.w, x3, at))));
            ar = fmaf(rv.x, x0, fmaf(rv.y, x1, fmaf(rv.z, x2, fmaf(rv.w, x3, ar))));
        }
        xn [b * SPAD + i] = at;
        x1b[b * SPAD + i] = ar;
    }
    __syncthreads();
    {
        const int b = tid >> 5, rr = tid & 31;
        float* row = xn + b * SPAD;
        float v0 = row[rr], v1 = row[rr + 32], v2 = row[rr + 64];
        float sum = v0 + v1 + v2, sq = fmaf(v0, v0, fmaf(v1, v1, v2 * v2));
        #pragma unroll
        for (int off = 16; off > 0; off >>= 1) {
            sum += __shfl_down(sum, off, 32);
            sq  += __shfl_down(sq,  off, 32);
        }
        sum = __shfl(sum, 0, 32); sq = __shfl(sq, 0, 32);
        float mu = sum * (1.0f/96.0f), var = fmaf(sq, 1.0f/96.0f, -(mu*mu));
        float rs = rsqrtf(var + 1e-5f);
        row[rr]      = fmaf((v0 - mu) * rs, g1[rr],      b1[rr]);
        row[rr + 32] = fmaf((v1 - mu) * rs, g1[rr + 32], b1[rr + 32]);
        row[rr + 64] = fmaf((v2 - mu) * rs, g1[rr + 64], b1[rr + 64]);
    }
    __syncthreads();
    for (int idx = tid; idx < B_SZ * D_OUT; idx += NT_W) {
        int i = idx >> 3, b = idx & 7;
        const float* wrow = w + i * SPAD;
        const float* xr   = xn + b * SPAD;
        float acc = 0.0f;
        #pragma unroll
        for (int j = 0; j < D_OUT / 4; ++j) {
            float4 wv = *(const float4*)(wrow + 4 * j);
            float4 xv = *(const float4*)(xr + 4 * j);
            acc = fmaf(wv.x, xv.x, fmaf(wv.y, xv.y, fmaf(wv.z, xv.z, fmaf(wv.w, xv.w, acc))));
        }
        x1b[b * SPAD + i] += acc;
    }
    __syncthreads();
    for (int e = tid; e < NE; e += NT_W) {
        float pl[8];
        *(float4*)&pl[0] = *(const float4*)(P2 + e * NB);
        *(float4*)&pl[4] = *(const float4*)(P2 + e * NB + 4);
        float acc = 0.0f;
        #pragma unroll
        for (int g = 0; g < NB; ++g) {
            float v = sf * __builtin_amdgcn_rcpf((float)(e * NB + 2 + g));
            acc = fmaf(pl[g], cos_rev(v), acc);
        }
        int i = e / D_OUT;
        w[e + (SPAD - D_OUT) * i] = acc;
    }
    for (int idx = tid; idx < B_SZ * D_OUT; idx += NT_W) {
        int i = idx >> 3, b = idx & 7;
        const float4* m  = (const float4*)(M2 + i * D_OUT);
        const float*  xr = x1b + b * SPAD;
        float at = 0.0f;
        #pragma unroll
        for (int k = 0; k < D_OUT / 4; ++k) {
            float4 mv = m[k];
            at = fmaf(mv.x, xr[4*k], fmaf(mv.y, xr[4*k+1],
                 fmaf(mv.z, xr[4*k+2], fmaf(mv.w, xr[4*k+3], at))));
        }
        xn[b * SPAD + i] = at;
    }
    __syncthreads();
    {
        const int b = tid >> 5, rr = tid & 31;
        float* row = xn + b * SPAD;
        float v0 = row[rr], v1 = row[rr + 32], v2 = row[rr + 64];
        float sum = v0 + v1 + v2, sq = fmaf(v0, v0, fmaf(v1, v1, v2 * v2));
        #pragma unroll
        for (int off = 16; off > 0; off >>= 1) {
            sum += __shfl_down(sum, off, 32);
            sq  += __shfl_down(sq,  off, 32);
        }
        sum = __shfl(sum, 0, 32); sq = __shfl(sq, 0, 32);
        float mu = sum * (1.0f/96.0f), var = fmaf(sq, 1.0f/96.0f, -(mu*mu));
        float rs = rsqrtf(var + 1e-5f);
        row[rr]      = fmaf((v0 - mu) * rs, g2[rr],      b2[rr]);
        row[rr + 32] = fmaf((v1 - mu) * rs, g2[rr + 32], b2[rr + 32]);
        row[rr + 64] = fmaf((v2 - mu) * rs, g2[rr + 64], b2[rr + 64]);
    }
    __syncthreads();
    for (int idx = tid; idx < B_SZ * D_OUT; idx += NT_W) {
        int i = idx >> 3, b = idx & 7;
        const float* wrow = w + i * SPAD;
        const float* xr   = xn + b * SPAD;
        float acc = 0.0f;
        #pragma unroll
        for (int j = 0; j < D_OUT / 4; ++j) {
            float4 wv = *(const float4*)(wrow + 4 * j);
            float4 xv = *(const float4*)(xr + 4 * j);
            acc = fmaf(wv.x, xv.x, fmaf(wv.y, xv.y, fmaf(wv.z, xv.z, fmaf(wv.w, xv.w, acc))));
        }
        out[(b * S_LEN + s) * D_OUT + i] = acc + x1b[b * SPAD + i];
    }
}

extern "C" void kernel_launch(void* const* d_in, const int* in_sizes, int n_in,
                              void* d_out, int out_size, void* d_ws, size_t ws_size,
                              hipStream_t stream) {
    const float* seq   = (const float*)d_in[0];
    const float* M1    = (const float*)d_in[1];
    const float* P1    = (const float*)d_in[2];
    const float* Wres1 = (const float*)d_in[3];
    const float* g1    = (const float*)d_in[4];
    const float* b1    = (const float*)d_in[5];
    const float* M2    = (const float*)d_in[6];
    const float* P2    = (const float*)d_in[7];
    const float* g2    = (const float*)d_in[8];
    const float* b2    = (const float*)d_in[9];
    float* out = (float*)d_out;

    const size_t need = (size_t)2 * S_LEN * NE * sizeof(__half);   // 37.75 MB
    if (ws_size >= need) {
        __half* W1 = (__half*)d_ws;
        __half* W2 = W1 + (size_t)S_LEN * NE;
        w_kernel<<<dim3(NWBLK), dim3(NT_W), 0, stream>>>(P1, P2, W1, W2);
        consumer<<<dim3(S_LEN), dim3(NT_C), 0, stream>>>(
            seq, M1, Wres1, M2, g1, b1, g2, b2, W1, W2, out);
    } else {
        hier_fallback<<<dim3(S_LEN), dim3(NT_W), 0, stream>>>(
            seq, M1, P1, Wres1, g1, b1, M2, P2, g2, b2, out);
    }
}